// Round 6
// baseline (677.502 us; speedup 1.0000x reference)
//
#include <hip/hip_runtime.h>

// Problem constants (reference: B=1024, P=128, KPASS=1)
#define PP 128        // P
#define H  127        // P-1 (hidden / MLP output dim)
#define NV 384        // 3 slots {Q,R,L} padded to 128 each
#define NB 1024       // batch

// Mathematical reduction of the reference:
//   out[b,r,c] = Theta[b,r,c]                                     if r==c
//              = 129*t12n[b,max(r,c),min(r,c)] - 128*Theta[b,r,c] otherwise
// t12n[b,col,:] = relu(feats(b,col)@W1 + b1) @ W2 + b2, feats from ORIGINAL
// Theta. Layer-1 via quadrant prefix decomposition, refactored to 3 vectors:
//   Q = P1-P2, R = P3, L = P4-P2  (per (b,k,o), dot of Th[b,k,:] with WQ/WR/WL)
//   z1[col] = b1 + prefexcl_k(Q)[col] + sufexcl_k(R)[col] + L[col]

// ---------------- Kernel A: build combined masked weights -------------------
__global__ __launch_bounds__(128) void build_wp(const float* __restrict__ W1,
                                                float* __restrict__ WP) {
  int bid = blockIdx.x;            // 16384 = 128k * 128c
  int k = bid >> 7, c = bid & 127;
  int o = threadIdx.x;             // 0..127 (o==127 is zero padding)
  float v1 = 0.f, v2 = 0.f, v3 = 0.f, v4 = 0.f;
  if (o < H) {
    if (k <= 126) {                // P1 (P1[127]=0)
      if (c < k)       v1 = W1[(k*H + c)*H + o]     + W1[(c*H + k)*H + o];
      else if (c == k) v1 = W1[(k*H + k)*H + o];
      else             v1 = W1[(k*H + (c-1))*H + o] + W1[((c-1)*H + k)*H + o];
    }
    if (k >= 1 && c < k)           // P2 (P2[0]=0)
      v2 = W1[(c*H + (k-1))*H + o] + W1[((k-1)*H + c)*H + o];
    if (k >= 1) {                  // P3 (P3[0]=0)
      if (c > k)       v3 = W1[((k-1)*H + (c-1))*H + o] + W1[((c-1)*H + (k-1))*H + o];
      else if (c == k) v3 = W1[((k-1)*H + (k-1))*H + o];
    }
    if (c < k)       v4 = W1[(16129 + c)*H + o];     // P4
    else if (c == k) v4 = W1[16256*H + o];
    else             v4 = W1[(16129 + (c-1))*H + o];
  }
  size_t base = (size_t)(k*PP + c) * NV;
  WP[base + o]       = v1 - v2;    // Q
  WP[base + 128 + o] = v3;         // R
  WP[base + 256 + o] = v4 - v2;    // L
}

// ---------------- Kernel T: Tht[k][c][bl] = Th[bbase+bl][k][c] --------------
__global__ __launch_bounds__(256) void transpose_th(const float* __restrict__ Th,
                                                    float* __restrict__ Tht,
                                                    int bbase, int BC) {
  __shared__ float tile[64][65];
  int c0 = blockIdx.x * 64, b0 = blockIdx.y * 64, k = blockIdx.z;
  int tid = threadIdx.x;
  int c4 = (tid & 15) * 4, r = tid >> 4;           // r 0..15
  for (int rr = 0; rr < 64; rr += 16) {
    float4 v = *(const float4*)&Th[((size_t)(bbase + b0 + r + rr) * PP + k) * PP + c0 + c4];
    tile[r + rr][c4 + 0] = v.x; tile[r + rr][c4 + 1] = v.y;
    tile[r + rr][c4 + 2] = v.z; tile[r + rr][c4 + 3] = v.w;
  }
  __syncthreads();
  int b4 = (tid & 15) * 4, cq = tid >> 4;
  for (int cc = 0; cc < 64; cc += 16) {
    int c = cq + cc;
    float4 v = make_float4(tile[b4 + 0][c], tile[b4 + 1][c],
                           tile[b4 + 2][c], tile[b4 + 3][c]);
    *(float4*)&Tht[((size_t)k * PP + c0 + c) * BC + b0 + b4] = v;
  }
}

// ---------------- Kernel B: P[bl][k][slot*128+o] = Th[b,k,:]·W*[k,:,o] ------
__global__ __launch_bounds__(256, 4) void pgemm(const float* __restrict__ Tht,
                                                const float* __restrict__ WP,
                                                float* __restrict__ P, int BC) {
  __shared__ float As[32 * 128];   // [cc][row_b]
  __shared__ float Bs[32 * 128];   // [cc][o]
  int nt = blockIdx.x, bt = blockIdx.y, k = blockIdx.z;
  int n0 = nt * 128;
  int tid = threadIdx.x;
  int tx = tid & 15, ty = tid >> 4;                // 16 x 16
  float acc[8][8] = {};
  for (int kc = 0; kc < 128; kc += 32) {
    {
      int p4 = (tid & 31) * 4, cc = tid >> 5;      // cc 0..7
      #pragma unroll
      for (int c2 = 0; c2 < 32; c2 += 8) {
        *(float4*)&As[(cc + c2) * 128 + p4] =
            *(const float4*)&Tht[((size_t)k * PP + kc + cc + c2) * BC + bt * 128 + p4];
        *(float4*)&Bs[(cc + c2) * 128 + p4] =
            *(const float4*)&WP[(size_t)(k * PP + kc + cc + c2) * NV + n0 + p4];
      }
    }
    __syncthreads();
    #pragma unroll
    for (int kk = 0; kk < 32; ++kk) {
      float4 a0 = *(const float4*)&As[kk * 128 + ty * 4];
      float4 a1 = *(const float4*)&As[kk * 128 + 64 + ty * 4];
      float4 b0 = *(const float4*)&Bs[kk * 128 + tx * 4];
      float4 b1 = *(const float4*)&Bs[kk * 128 + 64 + tx * 4];
      float av[8] = {a0.x, a0.y, a0.z, a0.w, a1.x, a1.y, a1.z, a1.w};
      float bv[8] = {b0.x, b0.y, b0.z, b0.w, b1.x, b1.y, b1.z, b1.w};
      #pragma unroll
      for (int i = 0; i < 8; ++i)
        #pragma unroll
        for (int j = 0; j < 8; ++j) acc[i][j] = fmaf(av[i], bv[j], acc[i][j]);
    }
    __syncthreads();
  }
  #pragma unroll
  for (int i = 0; i < 8; ++i) {
    int row = (i < 4) ? ty * 4 + i : 64 + ty * 4 + (i - 4);
    size_t base = ((size_t)(bt * 128 + row) * PP + k) * NV + n0;
    *(float4*)&P[base + tx * 4]      = make_float4(acc[i][0], acc[i][1], acc[i][2], acc[i][3]);
    *(float4*)&P[base + 64 + tx * 4] = make_float4(acc[i][4], acc[i][5], acc[i][6], acc[i][7]);
  }
}

// ---------------- Kernel C: register-resident scan + ReLU -> At[bl][j][col] -
__global__ __launch_bounds__(512, 4) void scan_c(const float* __restrict__ P,
                                                 float* __restrict__ At,
                                                 const float* __restrict__ b1) {
  __shared__ float zl[128 * 127];  // [col][o<127]
  float* ftot = zl;                // [s*128+o], dead before zl writes
  float* btot = zl + 512;
  int bl = blockIdx.x;
  int o = threadIdx.x & 127, s = threadIdx.x >> 7;
  const float* Pb = P + (size_t)bl * PP * NV;
  float q[32], r[32];
  float fa = 0.f, ba = 0.f;
  #pragma unroll
  for (int t = 0; t < 32; ++t) {
    int col = s * 32 + t;
    q[t] = Pb[col * NV + o];
    r[t] = Pb[col * NV + 128 + o];
    fa += q[t]; ba += r[t];
  }
  ftot[s * 128 + o] = fa;
  btot[s * 128 + o] = ba;
  __syncthreads();
  float fc = 0.f, bc = 0.f;
  for (int t = 0; t < s; ++t)     fc += ftot[t * 128 + o];
  for (int t = s + 1; t < 4; ++t) bc += btot[t * 128 + o];
  float b1v = (o < H) ? b1[o] : 0.f;
  __syncthreads();                 // carries read before zl overwrites ftot/btot
  float qp = 0.f, rinc = 0.f;
  #pragma unroll
  for (int t = 0; t < 32; ++t) {
    int col = s * 32 + t;
    float L = Pb[col * NV + 256 + o];
    rinc += r[t];                                  // inclusive R
    float z = b1v + fc + qp + bc + (ba - rinc) + L;
    qp += q[t];                                    // exclusive Q
    if (o < H) zl[col * 127 + o] = fmaxf(z, 0.f);
  }
  __syncthreads();
  float* Ab = At + (size_t)bl * PP * PP;
  for (int idx = threadIdx.x; idx < PP * PP; idx += 512) {
    int oo = idx >> 7, col = idx & 127;
    Ab[idx] = (oo < H) ? zl[col * 127 + oo] : 0.f; // At[oo][col], coalesced
  }
}

// ---------------- Kernel D1: t12[bl] = A @ W2 + b2 (pure GEMM, 32KB LDS) ----
__global__ __launch_bounds__(256, 4) void gemm_t12(const float* __restrict__ At,
                                                   const float* __restrict__ W2,
                                                   const float* __restrict__ b2,
                                                   float* __restrict__ t12) {
  __shared__ float Al[32 * 128];   // [jj][col]
  __shared__ float W2l[32 * 128];  // [jj][o]
  int bl = blockIdx.x;
  int tid = threadIdx.x;
  int tn = tid & 15, tm = tid >> 4;
  const float* Ab = At + (size_t)bl * PP * PP;
  float acc[8][8];
  #pragma unroll
  for (int i = 0; i < 8; ++i)
    #pragma unroll
    for (int j = 0; j < 8; ++j) {
      int oc = (j < 4) ? tn * 4 + j : 64 + tn * 4 + (j - 4);
      acc[i][j] = (oc < H) ? b2[oc] : 0.f;
    }
  for (int kc = 0; kc < 128; kc += 32) {
    {
      int c4 = (tid & 31) * 4, jj = tid >> 5;
      #pragma unroll
      for (int j2 = 0; j2 < 32; j2 += 8)
        *(float4*)&Al[(jj + j2) * 128 + c4] =
            *(const float4*)&Ab[(size_t)(kc + jj + j2) * 128 + c4];
      int oo = tid & 127, j0 = tid >> 7;           // 0..1
      #pragma unroll
      for (int j2 = 0; j2 < 32; j2 += 2) {
        int row = kc + j0 + j2;
        W2l[(j0 + j2) * 128 + oo] = (row < H && oo < H) ? W2[(size_t)row * H + oo] : 0.f;
      }
    }
    __syncthreads();
    #pragma unroll
    for (int kk = 0; kk < 32; ++kk) {
      float4 a0 = *(const float4*)&Al[kk * 128 + tm * 4];
      float4 a1 = *(const float4*)&Al[kk * 128 + 64 + tm * 4];
      float4 b0 = *(const float4*)&W2l[kk * 128 + tn * 4];
      float4 b1 = *(const float4*)&W2l[kk * 128 + 64 + tn * 4];
      float av[8] = {a0.x, a0.y, a0.z, a0.w, a1.x, a1.y, a1.z, a1.w};
      float bv[8] = {b0.x, b0.y, b0.z, b0.w, b1.x, b1.y, b1.z, b1.w};
      #pragma unroll
      for (int i = 0; i < 8; ++i)
        #pragma unroll
        for (int j = 0; j < 8; ++j) acc[i][j] = fmaf(av[i], bv[j], acc[i][j]);
    }
    __syncthreads();
  }
  #pragma unroll
  for (int i = 0; i < 8; ++i) {
    int row = (i < 4) ? tm * 4 + i : 64 + tm * 4 + (i - 4);
    size_t base = ((size_t)bl * PP + row) * PP;
    *(float4*)&t12[base + tn * 4]      = make_float4(acc[i][0], acc[i][1], acc[i][2], acc[i][3]);
    *(float4*)&t12[base + 64 + tn * 4] = make_float4(acc[i][4], acc[i][5], acc[i][6], acc[i][7]);
  }
}

// ---------------- Kernel D2: scatter out = 129*t12[max][min] - 128*Th -------
// 64x64 tile pairs: pi 0->(0,0) 1->(0,1) 2->(1,1); source S = t12 rows [R0,+64)
// cols [C0,+64) with R0=tj*64 >= C0=ti*64. Mirror (lower) tile from registers;
// upper/diag tile via one [64][65] LDS transpose (all reads conflict-free).
__global__ __launch_bounds__(256) void scatter(const float* __restrict__ t12,
                                               const float* __restrict__ Th,
                                               float* __restrict__ out, int bbase) {
  __shared__ float St[64 * 65];    // St[x*65+y] = S[y][x]
  int pi = blockIdx.x, bl = blockIdx.y, b = bbase + bl;
  int ti = (pi == 2) ? 1 : 0, tj = (pi == 0) ? 0 : 1;
  int R0 = tj * 64, C0 = ti * 64;
  const float* tb = t12 + (size_t)bl * PP * PP;
  const float* Tb = Th + (size_t)b * PP * PP;
  float* ob = out + (size_t)b * PP * PP;
  int t = threadIdx.x;
  int cc4 = (t & 15) * 4, rr = t >> 4;             // rr 0..15
  float4 s[4];
  #pragma unroll
  for (int g = 0; g < 4; ++g) {
    int r = rr + g * 16;
    s[g] = *(const float4*)&tb[(R0 + r) * PP + C0 + cc4];
    St[(cc4 + 0) * 65 + r] = s[g].x;
    St[(cc4 + 1) * 65 + r] = s[g].y;
    St[(cc4 + 2) * 65 + r] = s[g].z;
    St[(cc4 + 3) * 65 + r] = s[g].w;
  }
  if (pi == 1) {                   // mirror (strictly lower) tile, from regs
    #pragma unroll
    for (int g = 0; g < 4; ++g) {
      int r = R0 + rr + g * 16;
      float4 th = *(const float4*)&Tb[r * PP + C0 + cc4];
      float4 v = make_float4(129.f * s[g].x - 128.f * th.x,
                             129.f * s[g].y - 128.f * th.y,
                             129.f * s[g].z - 128.f * th.z,
                             129.f * s[g].w - 128.f * th.w);
      *(float4*)&ob[r * PP + C0 + cc4] = v;
    }
  }
  __syncthreads();
  // second tile: out rows [C0,+64), cols [R0,+64)
  #pragma unroll
  for (int g = 0; g < 4; ++g) {
    int rr2 = rr + g * 16;         // 0..63
    int r = C0 + rr2;
    int cb = R0 + cc4;
    float4 th = *(const float4*)&Tb[r * PP + cb];
    float thv[4] = {th.x, th.y, th.z, th.w};
    float v[4];
    #pragma unroll
    for (int i = 0; i < 4; ++i) {
      int cc2 = cc4 + i;
      float x;
      if (pi == 1)            x = 129.f * St[rr2 * 65 + cc2] - 128.f * thv[i];
      else if (cc2 > rr2)     x = 129.f * St[rr2 * 65 + cc2] - 128.f * thv[i];
      else if (cc2 < rr2)     x = 129.f * St[cc2 * 65 + rr2] - 128.f * thv[i];
      else                    x = thv[i];
      v[i] = x;
    }
    *(float4*)&ob[r * PP + cb] = make_float4(v[0], v[1], v[2], v[3]);
  }
}

extern "C" void kernel_launch(void* const* d_in, const int* in_sizes, int n_in,
                              void* d_out, int out_size, void* d_ws, size_t ws_size,
                              hipStream_t stream) {
  const float* Th = (const float*)d_in[0];
  const float* W1 = (const float*)d_in[1];
  const float* b1 = (const float*)d_in[2];
  const float* W2 = (const float*)d_in[3];
  const float* b2 = (const float*)d_in[4];
  // d_in[5..8] (D1,d1,D2,d2) provably do not affect the returned Theta.
  float* out = (float*)d_out;

  const size_t wp_elems = (size_t)PP * PP * NV;    // 6.29M floats = 25.2MB
  int BC = 1024;                                   // chunk: Tht/At + P must fit
  while (BC > 128 &&
         (wp_elems + (size_t)BC * PP * PP + (size_t)BC * PP * NV) * 4 > ws_size)
    BC >>= 1;

  float* WP  = (float*)d_ws;
  float* Tht = WP + wp_elems;                      // BC*16384 f; reused as At
  float* Pb  = Tht + (size_t)BC * PP * PP;         // BC*PP*NV f; t12 overlays

  build_wp<<<dim3(16384), dim3(128), 0, stream>>>(W1, WP);
  for (int bb = 0; bb < NB; bb += BC) {
    transpose_th<<<dim3(2, BC / 64, 128), dim3(256), 0, stream>>>(Th, Tht, bb, BC);
    pgemm<<<dim3(3, BC / 128, 128), dim3(256), 0, stream>>>(Tht, WP, Pb, BC);
    scan_c<<<dim3(BC), dim3(512), 0, stream>>>(Pb, Tht, b1);   // At overlays Tht
    gemm_t12<<<dim3(BC), dim3(256), 0, stream>>>(Tht, W2, b2, Pb);  // t12 -> Pb
    scatter<<<dim3(3, BC), dim3(256), 0, stream>>>(Pb, Th, out, bb);
  }
}